// Round 4
// baseline (173.958 us; speedup 1.0000x reference)
//
#include <hip/hip_runtime.h>
#include <cstdint>
#include <cstddef>

// ---------------------------------------------------------------------------
// LSTM cell, B=8192, D=H=512, fp32 in/out.
// pre = [x|h] @ Wstack^T + bias ; gates -> c_t, h_t fused in GEMM epilogue.
// Round 7: kill the A-pack. GEMM stages fp32 x/h straight into LDS via
// global_load_lds (K-step of 64 never straddles the x/h boundary at k=512)
// and converts to bf16 at fragment-read time with v_cvt_pk_bf16_f32 (RNE,
// same rounding as the old pack). Only the weights are pre-packed (12 MB,
// ~3 us mini-kernel) -- removes ~48 MB of pack traffic + the A HBM
// round-trip from the serial chain.
// GEMM geometry = r3's best: 256x128 tile, BK=64, 512 thr (8 waves, 64x64
// wave tiles), single-buffered LDS 80 KiB (A fp32 64K + B bf16 16K) ->
// exactly 2 blocks/CU, grid 512 all-resident.
// A swizzle (256B rows, 16 chunks): LDS pos p holds global chunk p^(row&15);
// frag read at (chunk^colA)*16 -> 8 lanes per bank-group = conflict-free
// minimum for wave64 b128. B keeps r3's proven c^(row&7) swizzle.
// Epilogue: h-interleaved B rows (n = h*4+gate) so each cell's (f,i,g,o) is
// one aligned float4 in LDS; stride 132 (4 rows == 16 mod 32 banks, 0 conf).
// ---------------------------------------------------------------------------

typedef __attribute__((ext_vector_type(8))) short short8;   // 8 bf16 = 4 VGPRs
typedef __attribute__((ext_vector_type(4))) float floatx4;  // MFMA acc

#define AS1(p) ((const __attribute__((address_space(1))) void*)(p))
#define AS3(p) ((__attribute__((address_space(3))) void*)(p))

__device__ __forceinline__ unsigned short f2bf(float f) {
  union { float f; unsigned u; } v; v.f = f;
  unsigned u = v.u;
  return (unsigned short)((u + 0x7fffu + ((u >> 16) & 1u)) >> 16);  // RNE
}

// --------------------------- pack weights only -----------------------------
// B[n][k], n = hh*4 + g (h-interleaved gates f,i,g,o), k<512 -> Wx else Wh;
// bias[n] = bx+bh.
struct PackBArgs {
  const float* wx[4]; const float* wh[4];
  const float* bx[4]; const float* bh[4];
  unsigned short* B; float* bias;
};

__global__ __launch_bounds__(256) void pack_b_kernel(PackBArgs P) {
  const int n  = blockIdx.x;          // 0..2047
  const int g  = n & 3, hh = n >> 2;
  const int k  = threadIdx.x * 4;
  const float* src = (k < 512) ? (P.wx[g] + hh * 512 + k)
                               : (P.wh[g] + hh * 512 + (k - 512));
  float4 v = *(const float4*)src;
  ushort4 o;
  o.x = f2bf(v.x); o.y = f2bf(v.y); o.z = f2bf(v.z); o.w = f2bf(v.w);
  *(ushort4*)(P.B + n * 1024 + k) = o;
  if (threadIdx.x == 0) P.bias[n] = P.bx[g][hh] + P.bh[g][hh];
}

// --------------------------- fused GEMM + LSTM epilogue --------------------
// Grid (32,16): tile = 256 batch x 128 cols (32 hidden x 4 gates). K=1024,
// BK=64 (16 steps; steps 0..7 read x, 8..15 read h).
// 512 threads = 8 waves (4M x 2N), wave tile 64x64.
// LDS: A fp32 [256][256B] @0 (64K), B bf16 [128][128B] @65536 (16K);
// epilogue ep[64][132] f32 (33792B) + biasE (512B @33792) overlay A.
__global__ __launch_bounds__(512, 4)
void lstm_gemm_kernel(const float* __restrict__ x,            // [8192][512]
                      const float* __restrict__ h_in,         // [8192][512]
                      const unsigned short* __restrict__ B,   // [2048][1024]
                      const float* __restrict__ bias,         // [2048]
                      const float* __restrict__ c_prev,       // [8192][512]
                      float* __restrict__ h_out,              // [8192][512]
                      float* __restrict__ c_out) {            // [8192][512]
  __shared__ __align__(16) char smem[81920];

  const int tid  = threadIdx.x;
  const int lane = tid & 63;
  const int w    = tid >> 6;        // wave 0..7
  const int quad = lane >> 4;
  const int colA = lane & 15;
  const int m0   = blockIdx.x * 256;
  const int n0   = blockIdx.y * 128;    // = h0*4
  const int h0   = blockIdx.y * 32;

  const int wm = (w >> 1) * 64;     // wave M offset (0,64,128,192)
  const int wn = (w & 1) * 64;      // wave N offset (0 or 64)

  // ---- staging geometry ----
  // A (fp32, 256B rows, 16 chunks): per instr 512 thr cover 32 rows.
  // LDS dest = j*8192 + tid*16 (linear); global chunk = p ^ (row&15).
  const int aRow = tid >> 4;                       // 0..31 (row within group)
  const int aSwz = ((tid & 15) ^ (aRow & 15)) * 16;
  // B (bf16, 128B rows, 8 chunks): per instr 512 thr cover 64 rows.
  const int srow = tid >> 3;                       // 0..63
  const int cl   = tid & 7;
  const int cg   = cl ^ (srow & 7);

  const char* Bg = (const char*)B;

  floatx4 acc[4][4];
#pragma unroll
  for (int i = 0; i < 4; ++i)
#pragma unroll
    for (int j = 0; j < 4; ++j) acc[i][j] = (floatx4){0.f, 0.f, 0.f, 0.f};

  for (int kt = 0; kt < 16; ++kt) {
    __syncthreads();                // prior LDS reads done
    const char* Asrc = (const char*)((kt < 8) ? x : h_in);
    const size_t kbA = (size_t)((kt & 7) * 256);   // byte offset in 2048B row
    const int    kbB = kt * 128;
#pragma unroll
    for (int j = 0; j < 8; ++j) {   // A: 256 rows fp32
      int r = j * 32 + aRow;
      __builtin_amdgcn_global_load_lds(
          AS1(Asrc + (size_t)(m0 + r) * 2048 + kbA + aSwz),
          AS3(smem + j * 8192 + tid * 16), 16, 0, 0);
    }
#pragma unroll
    for (int j = 0; j < 2; ++j) {   // B: 128 rows bf16 (h-interleaved)
      int r = j * 64 + srow;
      __builtin_amdgcn_global_load_lds(
          AS1(Bg + (size_t)(n0 + r) * 2048 + kbB + cg * 16),
          AS3(smem + 65536 + j * 8192 + tid * 16), 16, 0, 0);
    }
    __syncthreads();                // compiler drains vmcnt(0) here

#pragma unroll
    for (int kk = 0; kk < 2; ++kk) {
      // A frags: fp32 chunks e0, e0+1 (stored at pos^colA), cvt -> bf16
      const int e0   = kk * 8 + quad * 2;
      const int offA = (e0 ^ colA) * 16;
      short8 af[4];
#pragma unroll
      for (int mi = 0; mi < 4; ++mi) {
        const char* pa = smem + (wm + mi * 16 + colA) * 256;
        floatx4 lo = *(const floatx4*)(pa + offA);
        floatx4 hi = *(const floatx4*)(pa + (offA ^ 16));
        unsigned q0, q1, q2, q3;
        asm("v_cvt_pk_bf16_f32 %0, %1, %2" : "=v"(q0) : "v"(lo[0]), "v"(lo[1]));
        asm("v_cvt_pk_bf16_f32 %0, %1, %2" : "=v"(q1) : "v"(lo[2]), "v"(lo[3]));
        asm("v_cvt_pk_bf16_f32 %0, %1, %2" : "=v"(q2) : "v"(hi[0]), "v"(hi[1]));
        asm("v_cvt_pk_bf16_f32 %0, %1, %2" : "=v"(q3) : "v"(hi[2]), "v"(hi[3]));
        union { unsigned u[4]; short8 s; } cv;
        cv.u[0] = q0; cv.u[1] = q1; cv.u[2] = q2; cv.u[3] = q3;
        af[mi] = cv.s;
      }
      const int offB = ((kk * 4 + quad) ^ (colA & 7)) * 16;
      short8 bfr[4];
#pragma unroll
      for (int ni = 0; ni < 4; ++ni)
        bfr[ni] = *(const short8*)(smem + 65536 + (wn + ni * 16 + colA) * 128 + offB);
#pragma unroll
      for (int mi = 0; mi < 4; ++mi)
#pragma unroll
        for (int ni = 0; ni < 4; ++ni)
          acc[mi][ni] = __builtin_amdgcn_mfma_f32_16x16x32_bf16(
              af[mi], bfr[ni], acc[mi][ni], 0, 0, 0);
    }
  }

  // ------------------- fused epilogue (4 rounds of 64 M-rows) --------------
  __syncthreads();
  float* ep    = (float*)smem;            // [64][132] fp32, conflict-free
  float* biasE = (float*)(smem + 33792);  // [128], beyond ep region
  if (tid < 128) biasE[tid] = bias[n0 + tid];
#pragma unroll
  for (int rd = 0; rd < 4; ++rd) {
    // issue c_prev loads early; latency hides under ep writes + barrier
    float cp[4];
#pragma unroll
    for (int j = 0; j < 4; ++j) {
      int idx  = j * 512 + tid;     // 0..2047
      int mloc = idx >> 5;
      int hh   = idx & 31;
      cp[j] = c_prev[(m0 + rd * 64 + mloc) * 512 + h0 + hh];
    }
    if ((w >> 1) == rd) {           // the 2 waves with wm == rd*64
      // C/D layout: row = quad*4 + rr, col = lane&15
#pragma unroll
      for (int mi = 0; mi < 4; ++mi)
#pragma unroll
        for (int ni = 0; ni < 4; ++ni) {
          int rr0 = mi * 16 + quad * 4;                 // local row 0..63
          int cc  = wn + ni * 16 + colA;                // col 0..127
#pragma unroll
          for (int rr = 0; rr < 4; ++rr)
            ep[(rr0 + rr) * 132 + cc] = acc[mi][ni][rr];
        }
    }
    __syncthreads();
#pragma unroll
    for (int j = 0; j < 4; ++j) {
      int idx  = j * 512 + tid;     // 0..2047
      int mloc = idx >> 5;
      int hh   = idx & 31;
      // one aligned float4 = (f,i,g,o) pre-activations for this (m,h)
      float4 pre = *(const float4*)(ep + mloc * 132 + hh * 4);
      float4 bb  = *(const float4*)(biasE + hh * 4);
      float pf = pre.x + bb.x;
      float pi = pre.y + bb.y;
      float pg = pre.z + bb.z;
      float po = pre.w + bb.w;
      float fg = 1.f / (1.f + __expf(-pf));
      float ig = 1.f / (1.f + __expf(-pi));
      float gg = 1.f - 2.f / (1.f + __expf(2.f * pg));
      float og = 1.f / (1.f + __expf(-po));
      float cv = fg * cp[j] + ig * gg;
      float th = 1.f - 2.f / (1.f + __expf(2.f * cv));
      int m  = m0 + rd * 64 + mloc;
      int hg = h0 + hh;
      h_out[m * 512 + hg] = og * th;
      c_out[m * 512 + hg] = cv;
    }
    __syncthreads();
  }
}

// ---------------------------------------------------------------------------
extern "C" void kernel_launch(void* const* d_in, const int* in_sizes, int n_in,
                              void* d_out, int out_size, void* d_ws, size_t ws_size,
                              hipStream_t stream) {
  // workspace: B_bf16 (4 MiB) | bias (8 KiB)
  char* ws = (char*)d_ws;
  unsigned short* Bbf = (unsigned short*)ws;
  float* bias = (float*)(ws + (size_t)4194304);

  float* hout = (float*)d_out;
  float* cout = hout + (size_t)8192 * 512;

  PackBArgs P;
  // gate order: 0=f, 1=i, 2=g(cell), 3=o
  P.wx[0] = (const float*)d_in[3];  P.bx[0] = (const float*)d_in[4];
  P.wh[0] = (const float*)d_in[5];  P.bh[0] = (const float*)d_in[6];
  P.wx[1] = (const float*)d_in[7];  P.bx[1] = (const float*)d_in[8];
  P.wh[1] = (const float*)d_in[9];  P.bh[1] = (const float*)d_in[10];
  P.wx[2] = (const float*)d_in[11]; P.bx[2] = (const float*)d_in[12];
  P.wh[2] = (const float*)d_in[13]; P.bh[2] = (const float*)d_in[14];
  P.wx[3] = (const float*)d_in[15]; P.bx[3] = (const float*)d_in[16];
  P.wh[3] = (const float*)d_in[17]; P.bh[3] = (const float*)d_in[18];
  P.B = Bbf; P.bias = bias;

  pack_b_kernel<<<2048, 256, 0, stream>>>(P);

  const float* xin = (const float*)d_in[0];
  const float* hin = (const float*)d_in[1];
  const float* c   = (const float*)d_in[2];
  dim3 grid(32, 16);
  lstm_gemm_kernel<<<grid, 512, 0, stream>>>(xin, hin, Bbf, bias, c, hout, cout);
}